// Round 1
// baseline (431.105 us; speedup 1.0000x reference)
//
#include <hip/hip_runtime.h>
#include <hip/hip_bf16.h>

typedef short short8 __attribute__((ext_vector_type(8)));
typedef float f32x4 __attribute__((ext_vector_type(4)));

#define MFMA16(a,b,c) __builtin_amdgcn_mfma_f32_16x16x32_bf16((a),(b),(c),0,0,0)

__device__ __forceinline__ unsigned short f2bf(float f){
    union { float f; unsigned u; } v; v.f = f;
    unsigned r = v.u + 0x7FFFu + ((v.u >> 16) & 1u);
    return (unsigned short)(r >> 16);
}

union Frag {
    short8 s;
    unsigned short u[8];
    uint2 d2[2];
};

// ---------------------------------------------------------------------------
// Kernel 1: QKV projection. C[16384,192] = X[16384,512] @ [Wq|Wk|Wv] + bias.
// fp32 accumulate; emit bf16 q (pre-scaled by 1/8), k, and transposed vT.
// ---------------------------------------------------------------------------
__global__ __launch_bounds__(256) void qkv_kernel(
    const float* __restrict__ x,
    const float* __restrict__ Wq, const float* __restrict__ bqp,
    const float* __restrict__ Wk, const float* __restrict__ bkp,
    const float* __restrict__ Wv, const float* __restrict__ bvp,
    unsigned short* __restrict__ qb, unsigned short* __restrict__ kb,
    unsigned short* __restrict__ vtb)
{
    __shared__ float xs[64][33];
    __shared__ float ws[32][200];
    const int tid = threadIdx.x;
    const long row0 = (long)blockIdx.x * 64;
    const int ty = tid >> 4, tx = tid & 15;   // 16x16 thread grid

    float acc[4][12];
#pragma unroll
    for (int i = 0; i < 4; ++i)
#pragma unroll
        for (int j = 0; j < 12; ++j) acc[i][j] = 0.f;

    const int rr = tid >> 2;          // 0..63 (row for x staging)
    const int cc = (tid & 3) * 8;     // 0,8,16,24

    for (int kt = 0; kt < 16; ++kt) {
        // stage x tile [64][32]
        {
            const float* xp = x + (row0 + rr) * 512 + kt * 32 + cc;
            float4 v0 = *(const float4*)(xp);
            float4 v1 = *(const float4*)(xp + 4);
            xs[rr][cc + 0] = v0.x; xs[rr][cc + 1] = v0.y;
            xs[rr][cc + 2] = v0.z; xs[rr][cc + 3] = v0.w;
            xs[rr][cc + 4] = v1.x; xs[rr][cc + 5] = v1.y;
            xs[rr][cc + 6] = v1.z; xs[rr][cc + 7] = v1.w;
        }
        // stage W tile [32][192]  (cols 0-63: Wq, 64-127: Wk, 128-191: Wv)
#pragma unroll
        for (int i = 0; i < 24; ++i) {
            int e = i * 256 + tid;
            int c = e / 192;
            int j = e - c * 192;
            int krow = kt * 32 + c;
            float wv;
            if (j < 64)       wv = Wq[krow * 64 + j];
            else if (j < 128) wv = Wk[krow * 64 + j - 64];
            else              wv = Wv[krow * 64 + j - 128];
            ws[c][j] = wv;
        }
        __syncthreads();
#pragma unroll 8
        for (int c = 0; c < 32; ++c) {
            float a[4], b[12];
#pragma unroll
            for (int i = 0; i < 4; ++i) a[i] = xs[ty * 4 + i][c];
#pragma unroll
            for (int j = 0; j < 12; ++j) b[j] = ws[c][tx * 12 + j];
#pragma unroll
            for (int i = 0; i < 4; ++i)
#pragma unroll
                for (int j = 0; j < 12; ++j) acc[i][j] += a[i] * b[j];
        }
        __syncthreads();
    }

#pragma unroll
    for (int i = 0; i < 4; ++i) {
        long r = row0 + ty * 4 + i;
        int bi = (int)(r >> 12);
        int si = (int)(r & 4095);
#pragma unroll
        for (int j = 0; j < 12; ++j) {
            int col = tx * 12 + j;
            float v = acc[i][j];
            if (col < 64) {
                v = (v + bqp[col]) * 0.125f;      // fold 1/sqrt(64) into q
                qb[r * 64 + col] = f2bf(v);
            } else if (col < 128) {
                v += bkp[col - 64];
                kb[r * 64 + (col - 64)] = f2bf(v);
            } else {
                v += bvp[col - 128];
                vtb[((long)(bi * 64 + (col - 128))) * 4096 + si] = f2bf(v);
            }
        }
    }
}

// ---------------------------------------------------------------------------
// Kernel 2: flash attention. One wave per 16 q-rows. K-chunks of 64.
// Swapped QK^T: D = mfma(K, Q) puts scores in (col=q, row=t) layout which
// matches the PV A-operand layout after bf16 packing (no LDS transpose).
// ---------------------------------------------------------------------------
__global__ __launch_bounds__(64) void attn_kernel(
    const unsigned short* __restrict__ qb,
    const unsigned short* __restrict__ kb,
    const unsigned short* __restrict__ vtb,
    float* __restrict__ out)
{
    const int lane = threadIdx.x;
    const int qr = lane & 15;
    const int g  = lane >> 4;
    const long row0 = (long)blockIdx.x * 16;
    const int  bidx = (int)(row0 >> 12);
    const long kbase = (long)bidx * 4096;

    // Q B-operand fragments: lane holds q-row (row0+qr), d = 32*kk + 16*h + 4*g + j
    Frag bqf[2];
#pragma unroll
    for (int kk = 0; kk < 2; ++kk) {
        const unsigned short* p = qb + (row0 + qr) * 64 + 32 * kk + 4 * g;
        bqf[kk].d2[0] = *(const uint2*)(p);
        bqf[kk].d2[1] = *(const uint2*)(p + 16);
    }

    f32x4 acc[4];
#pragma unroll
    for (int dc = 0; dc < 4; ++dc) acc[dc] = (f32x4){0.f, 0.f, 0.f, 0.f};
    float m_run = -INFINITY, l_run = 0.f;

#pragma unroll 1
    for (int t0 = 0; t0 < 4096; t0 += 64) {
        // K A-operand fragments: row = t (16c + qr), k-dim = d
        Frag ka[4][2];
#pragma unroll
        for (int c = 0; c < 4; ++c) {
            const unsigned short* kp = kb + (kbase + t0 + 16 * c + qr) * 64 + 4 * g;
#pragma unroll
            for (int kk = 0; kk < 2; ++kk) {
                ka[c][kk].d2[0] = *(const uint2*)(kp + 32 * kk);
                ka[c][kk].d2[1] = *(const uint2*)(kp + 32 * kk + 16);
            }
        }
        // V B-operand fragments: col = d (16dc + qr), k-dim = t (from vT)
        Frag vb[4][2];
#pragma unroll
        for (int dc = 0; dc < 4; ++dc) {
            const unsigned short* vp =
                vtb + ((long)(bidx * 64 + 16 * dc + qr)) * 4096 + t0 + 4 * g;
#pragma unroll
            for (int kk = 0; kk < 2; ++kk) {
                vb[dc][kk].d2[0] = *(const uint2*)(vp + 32 * kk);
                vb[dc][kk].d2[1] = *(const uint2*)(vp + 32 * kk + 16);
            }
        }

        // scores: D[t][q], lane holds q=qr, t = t0 + 16c + 4g + reg
        float s_[4][4];
#pragma unroll
        for (int c = 0; c < 4; ++c) {
            f32x4 D = (f32x4){0.f, 0.f, 0.f, 0.f};
            D = MFMA16(ka[c][0].s, bqf[0].s, D);
            D = MFMA16(ka[c][1].s, bqf[1].s, D);
#pragma unroll
            for (int r = 0; r < 4; ++r) s_[c][r] = D[r];
        }

        // online softmax (per q-row qr; replicated across the 4 g-lanes)
        float mloc = -INFINITY;
#pragma unroll
        for (int c = 0; c < 4; ++c)
#pragma unroll
            for (int r = 0; r < 4; ++r) mloc = fmaxf(mloc, s_[c][r]);
        mloc = fmaxf(mloc, __shfl_xor(mloc, 16));
        mloc = fmaxf(mloc, __shfl_xor(mloc, 32));
        float m_new = fmaxf(m_run, mloc);
        float scale = __expf(m_run - m_new);   // first chunk: exp(-inf)=0

        float p_[4][4];
        float lloc = 0.f;
#pragma unroll
        for (int c = 0; c < 4; ++c)
#pragma unroll
            for (int r = 0; r < 4; ++r) {
                float p = __expf(s_[c][r] - m_new);
                p_[c][r] = p;
                lloc += p;
            }
        lloc += __shfl_xor(lloc, 16);
        lloc += __shfl_xor(lloc, 32);
        l_run = l_run * scale + lloc;
        m_run = m_new;

        // rescale O accumulator: its rows are q = 4g + r → fetch factors
        float f[4];
#pragma unroll
        for (int r = 0; r < 4; ++r) f[r] = __shfl(scale, 4 * g + r);
#pragma unroll
        for (int dc = 0; dc < 4; ++dc)
#pragma unroll
            for (int r = 0; r < 4; ++r) acc[dc][r] *= f[r];

        // pack P into PV A-operand: element j=4h+r ↔ t_local = 32kk+16h+4g+r
        Frag pa[2];
#pragma unroll
        for (int kk = 0; kk < 2; ++kk)
#pragma unroll
            for (int h = 0; h < 2; ++h)
#pragma unroll
                for (int r = 0; r < 4; ++r)
                    pa[kk].u[4 * h + r] = f2bf(p_[2 * kk + h][r]);

#pragma unroll
        for (int dc = 0; dc < 4; ++dc) {
            acc[dc] = MFMA16(pa[0].s, vb[dc][0].s, acc[dc]);
            acc[dc] = MFMA16(pa[1].s, vb[dc][1].s, acc[dc]);
        }
    }

    // epilogue: out rows q = 4g + r, cols d = 16dc + qr
    float linv[4];
#pragma unroll
    for (int r = 0; r < 4; ++r) linv[r] = 1.f / __shfl(l_run, 4 * g + r);
#pragma unroll
    for (int dc = 0; dc < 4; ++dc)
#pragma unroll
        for (int r = 0; r < 4; ++r)
            out[(row0 + 4 * g + r) * 64 + 16 * dc + qr] = acc[dc][r] * linv[r];
}

extern "C" void kernel_launch(void* const* d_in, const int* in_sizes, int n_in,
                              void* d_out, int out_size, void* d_ws, size_t ws_size,
                              hipStream_t stream) {
    (void)in_sizes; (void)n_in; (void)out_size; (void)ws_size;
    const float* x  = (const float*)d_in[0];
    const float* Wq = (const float*)d_in[1];
    const float* bq = (const float*)d_in[2];
    const float* Wk = (const float*)d_in[3];
    const float* bk = (const float*)d_in[4];
    const float* Wv = (const float*)d_in[5];
    const float* bv = (const float*)d_in[6];
    float* out = (float*)d_out;

    unsigned short* qb  = (unsigned short*)d_ws;
    unsigned short* kb  = qb + (size_t)16384 * 64;
    unsigned short* vtb = kb + (size_t)16384 * 64;

    hipLaunchKernelGGL(qkv_kernel, dim3(256), dim3(256), 0, stream,
                       x, Wq, bq, Wk, bk, Wv, bv, qb, kb, vtb);
    hipLaunchKernelGGL(attn_kernel, dim3(1024), dim3(64), 0, stream,
                       qb, kb, vtb, out);
}

// Round 2
// 80.944 us; speedup vs baseline: 5.3259x; 5.3259x over previous
//
#include <hip/hip_runtime.h>
#include <hip/hip_bf16.h>

typedef short short8 __attribute__((ext_vector_type(8)));
typedef float f32x4 __attribute__((ext_vector_type(4)));

#define MFMA16(a,b,c) __builtin_amdgcn_mfma_f32_16x16x32_bf16((a),(b),(c),0,0,0)

#define NROWS 16384

// d_ws byte offsets
#define OFF_Q  0u
#define OFF_K  (2u<<20)
#define OFF_V  (4u<<20)
#define OFF_W  (6u<<20)
#define OFF_O  ((6u<<20) + (1u<<18))
#define OFF_ML (OFF_O + (8u<<20))

__device__ __forceinline__ unsigned short f2bf(float f){
    union { float f; unsigned u; } v; v.f = f;
    unsigned r = v.u + 0x7FFFu + ((v.u >> 16) & 1u);
    return (unsigned short)(r >> 16);
}
__device__ __forceinline__ unsigned pack2(float a, float b){
    return (unsigned)f2bf(a) | ((unsigned)f2bf(b) << 16);
}

union Frag {
    short8 s;
    unsigned short u[8];
    uint2 d2[2];
    uint4 q4;
};

// ---------------------------------------------------------------------------
// W pre-fragmenter: wfrag[w(3)][nt(4)][kk(16)][lane(64)][8] bf16.
// Element: n = 16nt + (lane&15), k = 32kk + 16(e>>2) + 4(lane>>4) + (e&3).
// Serves BOTH as swapped-A (Q,K) and standard-B (V) operand. Wq ×0.125.
// ---------------------------------------------------------------------------
__global__ __launch_bounds__(256) void wprep_kernel(
    const float* __restrict__ Wq, const float* __restrict__ Wk,
    const float* __restrict__ Wv, unsigned short* __restrict__ wfrag)
{
    int idx = blockIdx.x * 256 + threadIdx.x;   // 0..12287
    int lane = idx & 63;
    int rest = idx >> 6;        // 0..191
    int kk = rest & 15;
    int nt = (rest >> 4) & 3;
    int w  = rest >> 6;         // 0..2
    const float* W = (w == 0) ? Wq : (w == 1) ? Wk : Wv;
    float scl = (w == 0) ? 0.125f : 1.0f;
    int n = 16 * nt + (lane & 15);
    int g = lane >> 4;
    Frag o;
#pragma unroll
    for (int e = 0; e < 8; ++e) {
        int k = 32 * kk + 16 * (e >> 2) + 4 * g + (e & 3);
        o.u[e] = f2bf(W[k * 64 + n] * scl);
    }
    *(uint4*)(wfrag + (size_t)idx * 8) = o.q4;
}

// ---------------------------------------------------------------------------
// QKV: pure-MFMA, LDS-free. Wave owns 16 seq rows (rg = bid*4 + wave).
// Q,K swapped: D = mfma(Wfrag, Xfrag) -> lane: col=seq(l&15), d=16nt+4g+r.
// V standard:  D = mfma(Xfrag, Wfrag) -> lane: col=d(l&15+16nt), seq=4g+r.
// Epilogue writes q/k/v in attention fragment order (8B packed stores).
// ---------------------------------------------------------------------------
__global__ __launch_bounds__(256, 1) void qkv_kernel(
    const float* __restrict__ x,
    const float* __restrict__ bq, const float* __restrict__ bk,
    const float* __restrict__ bv,
    const unsigned short* __restrict__ wfrag,
    unsigned short* __restrict__ qfrag,
    unsigned short* __restrict__ kfrag,
    unsigned short* __restrict__ vfrag)
{
    const int tid = threadIdx.x;
    const int lane = tid & 63;
    const int wv_ = tid >> 6;
    const int l15 = lane & 15, g = lane >> 4;
    const int rg = blockIdx.x * 4 + wv_;        // row-group 0..1023
    const long row = (long)rg * 16 + l15;

    f32x4 accQ[4], accK[4], accV[4];
#pragma unroll
    for (int nt = 0; nt < 4; ++nt) {
        accQ[nt] = (f32x4){0.f,0.f,0.f,0.f};
        accK[nt] = (f32x4){0.f,0.f,0.f,0.f};
        accV[nt] = (f32x4){0.f,0.f,0.f,0.f};
    }

    const uint4* wf = (const uint4*)wfrag;
    const float* xrow = x + row * 512;

#pragma unroll
    for (int kk = 0; kk < 16; ++kk) {
        Frag xf;
        float4 a0 = *(const float4*)(xrow + 32 * kk + 4 * g);
        float4 a1 = *(const float4*)(xrow + 32 * kk + 16 + 4 * g);
        xf.u[0] = f2bf(a0.x); xf.u[1] = f2bf(a0.y);
        xf.u[2] = f2bf(a0.z); xf.u[3] = f2bf(a0.w);
        xf.u[4] = f2bf(a1.x); xf.u[5] = f2bf(a1.y);
        xf.u[6] = f2bf(a1.z); xf.u[7] = f2bf(a1.w);

        Frag wqf[4], wkf[4], wvf[4];
#pragma unroll
        for (int nt = 0; nt < 4; ++nt) {
            wqf[nt].q4 = wf[((size_t)(0 * 4 + nt) * 16 + kk) * 64 + lane];
            wkf[nt].q4 = wf[((size_t)(1 * 4 + nt) * 16 + kk) * 64 + lane];
            wvf[nt].q4 = wf[((size_t)(2 * 4 + nt) * 16 + kk) * 64 + lane];
        }
#pragma unroll
        for (int nt = 0; nt < 4; ++nt) {
            accQ[nt] = MFMA16(wqf[nt].s, xf.s, accQ[nt]);
            accK[nt] = MFMA16(wkf[nt].s, xf.s, accK[nt]);
            accV[nt] = MFMA16(xf.s, wvf[nt].s, accV[nt]);
        }
    }

    const int b   = rg >> 8;
    const int rgb = rg & 255;
    const int tc  = rgb >> 2;
    const int c   = rgb & 3;

    // Q and K: lane holds d = 16nt + 4g + r for seq row (rg*16 + l15).
    // Target frag layout: d = 32ks + 16h + 4g + j  ->  ks=nt>>1, h=nt&1, j=r.
#pragma unroll
    for (int nt = 0; nt < 4; ++nt) {
        float4 bqv = *(const float4*)(bq + 16 * nt + 4 * g);
        float4 bkv = *(const float4*)(bk + 16 * nt + 4 * g);
        float q0 = accQ[nt][0] + bqv.x * 0.125f;
        float q1 = accQ[nt][1] + bqv.y * 0.125f;
        float q2 = accQ[nt][2] + bqv.z * 0.125f;
        float q3 = accQ[nt][3] + bqv.w * 0.125f;
        float k0 = accK[nt][0] + bkv.x;
        float k1 = accK[nt][1] + bkv.y;
        float k2 = accK[nt][2] + bkv.z;
        float k3 = accK[nt][3] + bkv.w;
        int ks = nt >> 1, h = nt & 1;
        size_t qoff = ((size_t)(rg * 2 + ks) * 64 + lane) * 8 + h * 4;
        *(uint2*)(qfrag + qoff) = make_uint2(pack2(q0, q1), pack2(q2, q3));
        size_t kfi = ((size_t)((b * 64 + tc) * 4 + c) * 2 + ks);
        size_t koff = (kfi * 64 + lane) * 8 + h * 4;
        *(uint2*)(kfrag + koff) = make_uint2(pack2(k0, k1), pack2(k2, k3));
    }
    // V: lane holds seq t_local = 16c + 4g + r for d col (16nt + l15).
    // Target frag: t = 32ks + 16h + 4g + j -> ks=c>>1, h=c&1, j=r.
    {
        const int vks = c >> 1, vh = c & 1;
#pragma unroll
        for (int nt = 0; nt < 4; ++nt) {
            float bvv = bv[16 * nt + l15];
            float v0 = accV[nt][0] + bvv;
            float v1 = accV[nt][1] + bvv;
            float v2 = accV[nt][2] + bvv;
            float v3 = accV[nt][3] + bvv;
            size_t vfi = ((size_t)((b * 64 + tc) * 4 + nt) * 2 + vks);
            size_t voff = (vfi * 64 + lane) * 8 + vh * 4;
            *(uint2*)(vfrag + voff) = make_uint2(pack2(v0, v1), pack2(v2, v3));
        }
    }
}

// ---------------------------------------------------------------------------
// Flash attention: 4 waves x 32 q-rows (QBLK=128), KV-split=2, grid 256.
// K/V chunk (64 t) staged to LDS in fragment order via global_load_lds x16
// (dwordx4), double-buffered, 1 barrier/chunk. ds_read_b128 lane-linear.
// ---------------------------------------------------------------------------
__global__ __launch_bounds__(256, 1) void attn_kernel(
    const unsigned short* __restrict__ qfrag,
    const unsigned short* __restrict__ kfrag,
    const unsigned short* __restrict__ vfrag,
    float* __restrict__ Opart, float* __restrict__ ml)
{
    __shared__ unsigned short lds[2][16][64][8];   // 32 KB
    const int tid = threadIdx.x;
    const int lane = tid & 63;
    const int w = tid >> 6;
    const int l15 = lane & 15, g = lane >> 4;
    const int qblock = blockIdx.x >> 1;
    const int split  = blockIdx.x & 1;
    const int qbase  = qblock * 128 + w * 32;
    const int b      = qbase >> 12;
    const int tcg0   = b * 64 + split * 32;    // global 64-chunk base

    Frag qf[2][2];
#pragma unroll
    for (int M = 0; M < 2; ++M) {
        int rg = (qbase >> 4) + M;
#pragma unroll
        for (int ks = 0; ks < 2; ++ks)
            qf[M][ks].q4 = *(const uint4*)(qfrag + ((size_t)(rg * 2 + ks) * 64 + lane) * 8);
    }

    f32x4 acc[2][4];
#pragma unroll
    for (int M = 0; M < 2; ++M)
#pragma unroll
        for (int dc = 0; dc < 4; ++dc) acc[M][dc] = (f32x4){0.f,0.f,0.f,0.f};
    float m_run[2] = {-INFINITY, -INFINITY};
    float l_run[2] = {0.f, 0.f};

    auto stage = [&](int ch, int buf) {
#pragma unroll
        for (int i = 0; i < 4; ++i) {
            int f = w * 4 + i;
            const unsigned short* src = (f < 8)
                ? (kfrag + (((size_t)(tcg0 + ch) * 8 + f) * 64 + lane) * 8)
                : (vfrag + (((size_t)(tcg0 + ch) * 8 + (f - 8)) * 64 + lane) * 8);
            __builtin_amdgcn_global_load_lds(
                (const __attribute__((address_space(1))) unsigned int*)src,
                (__attribute__((address_space(3))) unsigned int*)&lds[buf][f][0][0],
                16, 0, 0);
        }
    };

    stage(0, 0);
    __syncthreads();
    int cur = 0;

    for (int ch = 0; ch < 32; ++ch) {
        if (ch + 1 < 32) stage(ch + 1, cur ^ 1);

        Frag kf[4][2];
#pragma unroll
        for (int c = 0; c < 4; ++c)
#pragma unroll
            for (int ks = 0; ks < 2; ++ks)
                kf[c][ks].q4 = *(const uint4*)&lds[cur][c * 2 + ks][lane][0];

        // scores: D[t][q], lane q = l15, t = t0 + 16c + 4g + r
        f32x4 sD[2][4];
#pragma unroll
        for (int M = 0; M < 2; ++M)
#pragma unroll
            for (int c = 0; c < 4; ++c) {
                f32x4 D = (f32x4){0.f,0.f,0.f,0.f};
                D = MFMA16(kf[c][0].s, qf[M][0].s, D);
                D = MFMA16(kf[c][1].s, qf[M][1].s, D);
                sD[M][c] = D;
            }

        Frag vf[4][2];
#pragma unroll
        for (int dc = 0; dc < 4; ++dc)
#pragma unroll
            for (int ks = 0; ks < 2; ++ks)
                vf[dc][ks].q4 = *(const uint4*)&lds[cur][8 + dc * 2 + ks][lane][0];

        Frag pa[2][2];
#pragma unroll
        for (int M = 0; M < 2; ++M) {
            float mloc = -INFINITY;
#pragma unroll
            for (int c = 0; c < 4; ++c)
#pragma unroll
                for (int r = 0; r < 4; ++r) mloc = fmaxf(mloc, sD[M][c][r]);
            mloc = fmaxf(mloc, __shfl_xor(mloc, 16));
            mloc = fmaxf(mloc, __shfl_xor(mloc, 32));
            float m_new = fmaxf(m_run[M], mloc);
            float scale = __expf(m_run[M] - m_new);
            float p[4][4];
            float lloc = 0.f;
#pragma unroll
            for (int c = 0; c < 4; ++c)
#pragma unroll
                for (int r = 0; r < 4; ++r) {
                    float pv = __expf(sD[M][c][r] - m_new);
                    p[c][r] = pv; lloc += pv;
                }
            lloc += __shfl_xor(lloc, 16);
            lloc += __shfl_xor(lloc, 32);
            l_run[M] = l_run[M] * scale + lloc;
            m_run[M] = m_new;

            float fr[4];
#pragma unroll
            for (int r = 0; r < 4; ++r) fr[r] = __shfl(scale, 4 * g + r);
#pragma unroll
            for (int dc = 0; dc < 4; ++dc)
#pragma unroll
                for (int r = 0; r < 4; ++r) acc[M][dc][r] *= fr[r];

            // pack P: elem 4h+j <-> t_local = 32kk + 16h + 4g + j
#pragma unroll
            for (int kk = 0; kk < 2; ++kk)
#pragma unroll
                for (int h = 0; h < 2; ++h)
                    pa[M][kk].d2[h] = make_uint2(
                        pack2(p[2 * kk + h][0], p[2 * kk + h][1]),
                        pack2(p[2 * kk + h][2], p[2 * kk + h][3]));
        }

#pragma unroll
        for (int M = 0; M < 2; ++M)
#pragma unroll
            for (int dc = 0; dc < 4; ++dc) {
                acc[M][dc] = MFMA16(pa[M][0].s, vf[dc][0].s, acc[M][dc]);
                acc[M][dc] = MFMA16(pa[M][1].s, vf[dc][1].s, acc[M][dc]);
            }

        __syncthreads();
        cur ^= 1;
    }

    // partial output: rows q = qbase + 16M + 4g + r, cols d = 16dc + l15
#pragma unroll
    for (int M = 0; M < 2; ++M) {
        size_t rowb = (size_t)split * NROWS + qbase + 16 * M;
#pragma unroll
        for (int dc = 0; dc < 4; ++dc)
#pragma unroll
            for (int r = 0; r < 4; ++r)
                Opart[(rowb + 4 * g + r) * 64 + 16 * dc + l15] = acc[M][dc][r];
        if (g == 0) {
            ml[(rowb + l15) * 2 + 0] = m_run[M];
            ml[(rowb + l15) * 2 + 1] = l_run[M];
        }
    }
}

// ---------------------------------------------------------------------------
// Merge the two KV-split partials.
// ---------------------------------------------------------------------------
__global__ __launch_bounds__(256) void merge_kernel(
    const float* __restrict__ Opart, const float* __restrict__ ml,
    float* __restrict__ out)
{
    int gid = blockIdx.x * 256 + threadIdx.x;   // 0..262143
    int row = gid >> 4;
    int cg = (gid & 15) * 4;
    float m1 = ml[(size_t)row * 2],             l1 = ml[(size_t)row * 2 + 1];
    float m2 = ml[(size_t)(NROWS + row) * 2],   l2 = ml[(size_t)(NROWS + row) * 2 + 1];
    float mm = fmaxf(m1, m2);
    float e1 = __expf(m1 - mm), e2 = __expf(m2 - mm);
    float dn = 1.f / (l1 * e1 + l2 * e2);
    float4 o1 = *(const float4*)(Opart + (size_t)row * 64 + cg);
    float4 o2 = *(const float4*)(Opart + (size_t)(NROWS + row) * 64 + cg);
    float4 o;
    o.x = (o1.x * e1 + o2.x * e2) * dn;
    o.y = (o1.y * e1 + o2.y * e2) * dn;
    o.z = (o1.z * e1 + o2.z * e2) * dn;
    o.w = (o1.w * e1 + o2.w * e2) * dn;
    *(float4*)(out + (size_t)row * 64 + cg) = o;
}

extern "C" void kernel_launch(void* const* d_in, const int* in_sizes, int n_in,
                              void* d_out, int out_size, void* d_ws, size_t ws_size,
                              hipStream_t stream) {
    (void)in_sizes; (void)n_in; (void)out_size; (void)ws_size;
    const float* x  = (const float*)d_in[0];
    const float* Wq = (const float*)d_in[1];
    const float* bq = (const float*)d_in[2];
    const float* Wk = (const float*)d_in[3];
    const float* bk = (const float*)d_in[4];
    const float* Wv = (const float*)d_in[5];
    const float* bv = (const float*)d_in[6];
    float* out = (float*)d_out;

    char* ws = (char*)d_ws;
    unsigned short* qfrag = (unsigned short*)(ws + OFF_Q);
    unsigned short* kfrag = (unsigned short*)(ws + OFF_K);
    unsigned short* vfrag = (unsigned short*)(ws + OFF_V);
    unsigned short* wfrag = (unsigned short*)(ws + OFF_W);
    float* Opart = (float*)(ws + OFF_O);
    float* mlp   = (float*)(ws + OFF_ML);

    hipLaunchKernelGGL(wprep_kernel, dim3(48), dim3(256), 0, stream,
                       Wq, Wk, Wv, wfrag);
    hipLaunchKernelGGL(qkv_kernel, dim3(256), dim3(256), 0, stream,
                       x, bq, bk, bv, wfrag, qfrag, kfrag, vfrag);
    hipLaunchKernelGGL(attn_kernel, dim3(256), dim3(256), 0, stream,
                       qfrag, kfrag, vfrag, Opart, mlp);
    hipLaunchKernelGGL(merge_kernel, dim3(1024), dim3(256), 0, stream,
                       Opart, mlp, out);
}